// Round 11
// baseline (382.688 us; speedup 1.0000x reference)
//
#include <hip/hip_runtime.h>
#include <hip/hip_bf16.h>

#define NNODES 50000
#define NEDGES 800000
#define HIDDIM 128
#define NGRAPH 64
#define BUCKET 64  // fixed CSR bucket capacity (mean deg 16, P(deg>=64)~2e-18)

typedef __attribute__((ext_vector_type(8))) short short8;
typedef __attribute__((ext_vector_type(4))) float floatx4;

__device__ __forceinline__ float bfbits2f(unsigned short u) {
    return __uint_as_float(((unsigned int)u) << 16);
}
__device__ __forceinline__ unsigned short f2bfbits(float v) {
    __hip_bfloat16 h = __float2bfloat16(v);
    return __builtin_bit_cast(unsigned short, h);
}

// ---------------- runtime dtype detection (parallel) ----------------
// flags[0]=1: floats stored bf16; 0: fp32.  flags[1]=1: indices int64; 0: int32.
__global__ void k_detect(const unsigned int* __restrict__ xw,
                         const unsigned int* __restrict__ eiw,
                         int* __restrict__ flags) {
    __shared__ int sh_hit, sh_zero;
    int t = threadIdx.x;
    if (t == 0) { sh_hit = 0; sh_zero = 0; }
    __syncthreads();
    if (t < 128) {
        unsigned int w = xw[t * 97 + 5];
        int e = (int)((w >> 7) & 0xFF);
        if (e >= 110 && e <= 140) atomicAdd(&sh_hit, 1);
        if (eiw[1001 + 2 * t] == 0) atomicAdd(&sh_zero, 1);
    }
    __syncthreads();
    if (t == 0) {
        flags[0] = (sh_hit >= 64) ? 1 : 0;
        flags[1] = (sh_zero >= 120) ? 1 : 0;
    }
}

__device__ __forceinline__ int ld_idx(const int* __restrict__ p, int j, int wide) {
    return wide ? p[2 * j] : p[j];
}

__device__ __forceinline__ int find_bound(const int* __restrict__ batch, int wide, int g) {
    int lo = 0, hi = NNODES;
    while (lo < hi) {
        int mid = (lo + hi) >> 1;
        if (ld_idx(batch, mid, wide) < g) lo = mid + 1; else hi = mid;
    }
    return lo;
}

// ---------------- bucket-CSR build (single append pass, ushort entries) ------------
__global__ void k_zero_int(int* __restrict__ p, int n) {
    int i = blockIdx.x * 256 + threadIdx.x;
    if (i < n) p[i] = 0;
}

__global__ void k_append(const int* __restrict__ ei, const int* __restrict__ flags,
                         int* __restrict__ cnt, unsigned short* __restrict__ ecol) {
    int t = blockIdx.x * 256 + threadIdx.x;
    int e0 = t * 2;
    if (e0 >= NEDGES) return;
    int wide = flags[1];
    int s0, s1, d0, d1;
    if (wide) {
        int4 sv = ((const int4*)ei)[t];
        s0 = sv.x; s1 = sv.z;
        int4 dv = ((const int4*)(ei + 2 * NEDGES))[t];
        d0 = dv.x; d1 = dv.z;
    } else {
        int2 sv = ((const int2*)ei)[t];
        s0 = sv.x; s1 = sv.y;
        int2 dv = ((const int2*)(ei + NEDGES))[t];
        d0 = dv.x; d1 = dv.y;
    }
    int p0 = atomicAdd(&cnt[d0], 1);
    if (p0 < BUCKET) ecol[d0 * BUCKET + p0] = (unsigned short)s0;
    int p1 = atomicAdd(&cnt[d1], 1);
    if (p1 < BUCKET) ecol[d1 * BUCKET + p1] = (unsigned short)s1;
}

// ---------------- MFMA GEMM: out_bf16[M,128] = (A @ W) * rsqrt(cnt[m]+1)? ----------
// a_mode: 0=fp32 A, 1=A follows flags[0], 2=A is bf16 bits.  cntScale nullable.
__global__ __launch_bounds__(256) void k_gemm_mfma(const void* __restrict__ A,
                                                   const void* __restrict__ W,
                                                   const int* __restrict__ flags,
                                                   int a_mode,
                                                   const int* __restrict__ cntScale,
                                                   unsigned short* __restrict__ out,
                                                   int M) {
    __shared__ __align__(16) unsigned short Wl[16 * 128 * 8];   // 32 KB: [kb][n][j]
    __shared__ __align__(16) unsigned short Alds[64 * 17 * 8];  // 17 KB: [m][kb(+pad)][j]
    const int tid = threadIdx.x;
    const int F = flags[0];
    const int abf = (a_mode == 2) ? 1 : (a_mode == 1 ? F : 0);
    const int row0 = blockIdx.x * 64;

    if (F) {
        const ushort4* __restrict__ Wg = (const ushort4*)W;
#pragma unroll
        for (int it = 0; it < 16; ++it) {
            int idx = it * 256 + tid;
            int k = idx >> 5, n = (idx & 31) * 4;
            ushort4 wv = Wg[idx];
            unsigned short* dst = &Wl[(((k >> 3) * 128) + n) * 8 + (k & 7)];
            dst[0] = wv.x; dst[8] = wv.y; dst[16] = wv.z; dst[24] = wv.w;
        }
    } else {
        const float4* __restrict__ Wg = (const float4*)W;
#pragma unroll
        for (int it = 0; it < 16; ++it) {
            int idx = it * 256 + tid;
            int k = idx >> 5, n = (idx & 31) * 4;
            float4 wv = Wg[idx];
            unsigned short* dst = &Wl[(((k >> 3) * 128) + n) * 8 + (k & 7)];
            dst[0] = f2bfbits(wv.x); dst[8]  = f2bfbits(wv.y);
            dst[16] = f2bfbits(wv.z); dst[24] = f2bfbits(wv.w);
        }
    }
    if (abf) {
#pragma unroll
        for (int it = 0; it < 4; ++it) {
            int idx = it * 256 + tid;
            int m = idx >> 4, kb = idx & 15;
            int gr = row0 + m;
            uint4 v = make_uint4(0, 0, 0, 0);
            if (gr < M) v = ((const uint4*)A)[(size_t)gr * 16 + kb];
            *reinterpret_cast<uint4*>(&Alds[(m * 17 + kb) * 8]) = v;
        }
    } else {
#pragma unroll
        for (int it = 0; it < 8; ++it) {
            int idx = it * 256 + tid;
            int m = idx >> 5, k4 = idx & 31;
            int k = k4 * 4;
            int gr = row0 + m;
            float4 v = make_float4(0, 0, 0, 0);
            if (gr < M) v = ((const float4*)A)[(size_t)gr * 32 + k4];
            ushort4 u;
            u.x = f2bfbits(v.x); u.y = f2bfbits(v.y);
            u.z = f2bfbits(v.z); u.w = f2bfbits(v.w);
            *reinterpret_cast<ushort4*>(&Alds[(m * 17 + (k >> 3)) * 8 + (k & 7)]) = u;
        }
    }
    __syncthreads();

    const int lane = tid & 63;
    const int wave = tid >> 6;
    const int q = lane >> 4;
    const int c = lane & 15;
    const int mrow = wave * 16 + c;
    floatx4 acc[8] = {};
#pragma unroll
    for (int k0 = 0; k0 < 4; ++k0) {
        int kb = k0 * 4 + q;
        short8 afrag = *reinterpret_cast<const short8*>(&Alds[(mrow * 17 + kb) * 8]);
#pragma unroll
        for (int t = 0; t < 8; ++t) {
            short8 bfrag = *reinterpret_cast<const short8*>(&Wl[(kb * 128 + t * 16 + c) * 8]);
            acc[t] = __builtin_amdgcn_mfma_f32_16x16x32_bf16(afrag, bfrag, acc[t], 0, 0, 0);
        }
    }
#pragma unroll
    for (int i = 0; i < 4; ++i) {
        int gr = row0 + wave * 16 + q * 4 + i;
        if (gr < M) {
            float s = cntScale ? rsqrtf((float)cntScale[gr] + 1.0f) : 1.0f;
#pragma unroll
            for (int t = 0; t < 8; ++t) {
                out[(size_t)gr * 128 + t * 16 + c] = f2bfbits(acc[t][i] * s);
            }
        }
    }
}

// ---------------- FUSED layer: h = relu(gather(tmp)*dinv + b); out = (h@W)*dinv ------
// Gather phase writes h directly into the MFMA A-tile in LDS (never hits global).
// Column c=4j+i -> kb=j>>1, kj=(j&1)*4+i in the A-layout.
__global__ __launch_bounds__(256) void k_fused(const unsigned short* __restrict__ tmp16,
                                               const void* __restrict__ W,
                                               const int* __restrict__ flags,
                                               const int* __restrict__ cnt,
                                               const unsigned short* __restrict__ ecol,
                                               const void* __restrict__ bias,
                                               unsigned short* __restrict__ out,
                                               int M) {
    __shared__ __align__(16) unsigned short Wl[16 * 128 * 8];   // 32 KB
    __shared__ __align__(16) unsigned short Alds[64 * 17 * 8];  // 17 KB
    const int tid = threadIdx.x;
    const int F = flags[0];
    const int row0 = blockIdx.x * 64;

    // stage W
    if (F) {
        const ushort4* __restrict__ Wg = (const ushort4*)W;
#pragma unroll
        for (int it = 0; it < 16; ++it) {
            int idx = it * 256 + tid;
            int k = idx >> 5, n = (idx & 31) * 4;
            ushort4 wv = Wg[idx];
            unsigned short* dst = &Wl[(((k >> 3) * 128) + n) * 8 + (k & 7)];
            dst[0] = wv.x; dst[8] = wv.y; dst[16] = wv.z; dst[24] = wv.w;
        }
    } else {
        const float4* __restrict__ Wg = (const float4*)W;
#pragma unroll
        for (int it = 0; it < 16; ++it) {
            int idx = it * 256 + tid;
            int k = idx >> 5, n = (idx & 31) * 4;
            float4 wv = Wg[idx];
            unsigned short* dst = &Wl[(((k >> 3) * 128) + n) * 8 + (k & 7)];
            dst[0] = f2bfbits(wv.x); dst[8]  = f2bfbits(wv.y);
            dst[16] = f2bfbits(wv.z); dst[24] = f2bfbits(wv.w);
        }
    }

    // gather phase: 8 rows concurrently (32 threads/row), 8 iterations
    const int r8 = tid >> 5, j = tid & 31;
    float b0, b1, b2, b3;
    if (F) {
        const unsigned short* bb = (const unsigned short*)bias;
        b0 = bfbits2f(bb[j * 4 + 0]); b1 = bfbits2f(bb[j * 4 + 1]);
        b2 = bfbits2f(bb[j * 4 + 2]); b3 = bfbits2f(bb[j * 4 + 3]);
    } else {
        const float* bb = (const float*)bias;
        b0 = bb[j * 4 + 0]; b1 = bb[j * 4 + 1]; b2 = bb[j * 4 + 2]; b3 = bb[j * 4 + 3];
    }
    const ushort4* __restrict__ base = reinterpret_cast<const ushort4*>(tmp16);
#pragma unroll
    for (int it = 0; it < 8; ++it) {
        int m = it * 8 + r8;
        int n = row0 + m;
        float ax = 0, ay = 0, az = 0, aw = 0;
        if (n < M) {
            int rawc = cnt[n];
            int deg = rawc > BUCKET ? BUCKET : rawc;
            ushort4 u = base[(size_t)n * 32 + j];  // self (pre-scaled)
            ax = bfbits2f(u.x); ay = bfbits2f(u.y);
            az = bfbits2f(u.z); aw = bfbits2f(u.w);
            const unsigned short* __restrict__ bk = &ecol[n * BUCKET];
            int k = 0;
            for (; k + 3 < deg; k += 4) {
                ushort4 sv = *reinterpret_cast<const ushort4*>(&bk[k]);
                ushort4 u0 = base[(size_t)sv.x * 32 + j];
                ushort4 u1 = base[(size_t)sv.y * 32 + j];
                ushort4 u2 = base[(size_t)sv.z * 32 + j];
                ushort4 u3 = base[(size_t)sv.w * 32 + j];
                ax += (bfbits2f(u0.x) + bfbits2f(u1.x)) + (bfbits2f(u2.x) + bfbits2f(u3.x));
                ay += (bfbits2f(u0.y) + bfbits2f(u1.y)) + (bfbits2f(u2.y) + bfbits2f(u3.y));
                az += (bfbits2f(u0.z) + bfbits2f(u1.z)) + (bfbits2f(u2.z) + bfbits2f(u3.z));
                aw += (bfbits2f(u0.w) + bfbits2f(u1.w)) + (bfbits2f(u2.w) + bfbits2f(u3.w));
            }
            for (; k < deg; ++k) {
                ushort4 u0 = base[(size_t)bk[k] * 32 + j];
                ax += bfbits2f(u0.x); ay += bfbits2f(u0.y);
                az += bfbits2f(u0.z); aw += bfbits2f(u0.w);
            }
            float dn = rsqrtf((float)rawc + 1.0f);
            ax = fmaxf(ax * dn + b0, 0.0f);
            ay = fmaxf(ay * dn + b1, 0.0f);
            az = fmaxf(az * dn + b2, 0.0f);
            aw = fmaxf(aw * dn + b3, 0.0f);
        }
        ushort4 o;
        o.x = f2bfbits(ax); o.y = f2bfbits(ay);
        o.z = f2bfbits(az); o.w = f2bfbits(aw);
        *reinterpret_cast<ushort4*>(&Alds[(m * 17 + (j >> 1)) * 8 + (j & 1) * 4]) = o;
    }
    __syncthreads();

    // MFMA phase
    const int lane = tid & 63;
    const int wave = tid >> 6;
    const int q = lane >> 4;
    const int c = lane & 15;
    const int mrow = wave * 16 + c;
    floatx4 acc[8] = {};
#pragma unroll
    for (int k0 = 0; k0 < 4; ++k0) {
        int kb = k0 * 4 + q;
        short8 afrag = *reinterpret_cast<const short8*>(&Alds[(mrow * 17 + kb) * 8]);
#pragma unroll
        for (int t = 0; t < 8; ++t) {
            short8 bfrag = *reinterpret_cast<const short8*>(&Wl[(kb * 128 + t * 16 + c) * 8]);
            acc[t] = __builtin_amdgcn_mfma_f32_16x16x32_bf16(afrag, bfrag, acc[t], 0, 0, 0);
        }
    }
#pragma unroll
    for (int i = 0; i < 4; ++i) {
        int gr = row0 + wave * 16 + q * 4 + i;
        if (gr < M) {
            float s = rsqrtf((float)cnt[gr] + 1.0f);
#pragma unroll
            for (int t = 0; t < 8; ++t) {
                out[(size_t)gr * 128 + t * 16 + c] = f2bfbits(acc[t][i] * s);
            }
        }
    }
}

// ---------------- standalone gather (final layer): bf16 in/out ----------------
__global__ __launch_bounds__(256) void k_gather(const int* __restrict__ cnt,
                                                const unsigned short* __restrict__ ecol,
                                                const unsigned short* __restrict__ tmp16,
                                                const void* __restrict__ bias,
                                                const int* __restrict__ flags,
                                                unsigned short* __restrict__ outh16) {
    int t = blockIdx.x * 256 + threadIdx.x;
    int n = t >> 5;
    if (n >= NNODES) return;
    int j = t & 31;
    int rawc = cnt[n];
    int deg = rawc > BUCKET ? BUCKET : rawc;
    const unsigned short* __restrict__ bk = &ecol[n * BUCKET];
    const ushort4* __restrict__ base = reinterpret_cast<const ushort4*>(tmp16);
    ushort4 u = base[(size_t)n * 32 + j];
    float ax = bfbits2f(u.x), ay = bfbits2f(u.y), az = bfbits2f(u.z), aw = bfbits2f(u.w);
    int k = 0;
    for (; k + 3 < deg; k += 4) {
        ushort4 sv = *reinterpret_cast<const ushort4*>(&bk[k]);
        ushort4 u0 = base[(size_t)sv.x * 32 + j];
        ushort4 u1 = base[(size_t)sv.y * 32 + j];
        ushort4 u2 = base[(size_t)sv.z * 32 + j];
        ushort4 u3 = base[(size_t)sv.w * 32 + j];
        ax += (bfbits2f(u0.x) + bfbits2f(u1.x)) + (bfbits2f(u2.x) + bfbits2f(u3.x));
        ay += (bfbits2f(u0.y) + bfbits2f(u1.y)) + (bfbits2f(u2.y) + bfbits2f(u3.y));
        az += (bfbits2f(u0.z) + bfbits2f(u1.z)) + (bfbits2f(u2.z) + bfbits2f(u3.z));
        aw += (bfbits2f(u0.w) + bfbits2f(u1.w)) + (bfbits2f(u2.w) + bfbits2f(u3.w));
    }
    for (; k < deg; ++k) {
        ushort4 u0 = base[(size_t)bk[k] * 32 + j];
        ax += bfbits2f(u0.x); ay += bfbits2f(u0.y);
        az += bfbits2f(u0.z); aw += bfbits2f(u0.w);
    }
    float dn = rsqrtf((float)rawc + 1.0f);
    ax *= dn; ay *= dn; az *= dn; aw *= dn;
    float b0, b1, b2, b3;
    if (flags[0]) {
        const unsigned short* bb = (const unsigned short*)bias;
        b0 = bfbits2f(bb[j * 4 + 0]); b1 = bfbits2f(bb[j * 4 + 1]);
        b2 = bfbits2f(bb[j * 4 + 2]); b3 = bfbits2f(bb[j * 4 + 3]);
    } else {
        const float* bb = (const float*)bias;
        b0 = bb[j * 4 + 0]; b1 = bb[j * 4 + 1]; b2 = bb[j * 4 + 2]; b3 = bb[j * 4 + 3];
    }
    ushort4 o;
    o.x = f2bfbits(fmaxf(ax + b0, 0.0f));
    o.y = f2bfbits(fmaxf(ay + b1, 0.0f));
    o.z = f2bfbits(fmaxf(az + b2, 0.0f));
    o.w = f2bfbits(fmaxf(aw + b3, 0.0f));
    reinterpret_cast<ushort4*>(outh16)[(size_t)n * 32 + j] = o;
}

// ---------------- fallback (round-3 proven) atomic-scatter path ----------------
__global__ __launch_bounds__(256) void k_gemm(const void* __restrict__ A,
                                              const void* __restrict__ W,
                                              const int* __restrict__ flags,
                                              int a_uses_flag,
                                              float* __restrict__ out, int M) {
    __shared__ __align__(16) float Al[32 * 128];
    const int tid = threadIdx.x;
    const int F = flags[0];
    const int afmt = a_uses_flag ? F : 0;
    const int row0 = blockIdx.x * 32;
#pragma unroll
    for (int j = 0; j < 16; ++j) {
        int idx = j * 256 + tid;
        int r = idx >> 7, k = idx & 127;
        int gr = row0 + r;
        float v = 0.0f;
        if (gr < M) {
            size_t off = (size_t)gr * 128 + k;
            v = afmt ? bfbits2f(((const unsigned short*)A)[off])
                     : ((const float*)A)[off];
        }
        Al[idx] = v;
    }
    __syncthreads();
    const int tx = tid & 31, ty = tid >> 5;
    const int c0 = tx * 4;
    float acc[4][4] = {};
    if (F) {
        const ushort4* __restrict__ Wg = (const ushort4*)W;
#pragma unroll 4
        for (int k = 0; k < 128; ++k) {
            ushort4 wv = Wg[k * 32 + tx];
            float w0 = bfbits2f(wv.x), w1 = bfbits2f(wv.y);
            float w2 = bfbits2f(wv.z), w3 = bfbits2f(wv.w);
#pragma unroll
            for (int i = 0; i < 4; ++i) {
                float a = Al[(ty + i * 8) * 128 + k];
                acc[i][0] = fmaf(a, w0, acc[i][0]);
                acc[i][1] = fmaf(a, w1, acc[i][1]);
                acc[i][2] = fmaf(a, w2, acc[i][2]);
                acc[i][3] = fmaf(a, w3, acc[i][3]);
            }
        }
    } else {
        const float4* __restrict__ Wg = (const float4*)W;
#pragma unroll 4
        for (int k = 0; k < 128; ++k) {
            float4 wv = Wg[k * 32 + tx];
#pragma unroll
            for (int i = 0; i < 4; ++i) {
                float a = Al[(ty + i * 8) * 128 + k];
                acc[i][0] = fmaf(a, wv.x, acc[i][0]);
                acc[i][1] = fmaf(a, wv.y, acc[i][1]);
                acc[i][2] = fmaf(a, wv.z, acc[i][2]);
                acc[i][3] = fmaf(a, wv.w, acc[i][3]);
            }
        }
    }
#pragma unroll
    for (int i = 0; i < 4; ++i) {
        int gr = row0 + ty + i * 8;
        if (gr < M) {
            *reinterpret_cast<float4*>(&out[(size_t)gr * 128 + c0]) =
                make_float4(acc[i][0], acc[i][1], acc[i][2], acc[i][3]);
        }
    }
}
__global__ void k_deg_init(float* __restrict__ deg) {
    int i = blockIdx.x * 256 + threadIdx.x;
    if (i < NNODES) deg[i] = 1.0f;
}
__global__ void k_deg_edges(const int* __restrict__ ei, const int* __restrict__ flags,
                            float* __restrict__ deg) {
    int e = blockIdx.x * 256 + threadIdx.x;
    if (e < NEDGES) unsafeAtomicAdd(&deg[ld_idx(ei, NEDGES + e, flags[1])], 1.0f);
}
__global__ void k_rsqrt(float* __restrict__ deg) {
    int i = blockIdx.x * 256 + threadIdx.x;
    if (i < NNODES) deg[i] = 1.0f / sqrtf(deg[i]);
}
__global__ void k_selfloop(const float* __restrict__ tmp, const float* __restrict__ dinv,
                           float* __restrict__ agg) {
    int t = blockIdx.x * 256 + threadIdx.x;
    if (t >= NNODES * 32) return;
    int n = t >> 5, j = t & 31;
    float s = dinv[n]; s = s * s;
    float4 v = *reinterpret_cast<const float4*>(&tmp[(size_t)n * 128 + j * 4]);
    v.x *= s; v.y *= s; v.z *= s; v.w *= s;
    *reinterpret_cast<float4*>(&agg[(size_t)n * 128 + j * 4]) = v;
}
__global__ __launch_bounds__(256) void k_scatter(const int* __restrict__ ei,
                                                 const int* __restrict__ flags,
                                                 const float* __restrict__ dinv,
                                                 const float* __restrict__ tmp,
                                                 float* __restrict__ agg) {
    int t = blockIdx.x * 256 + threadIdx.x;
    int e = t >> 5;
    if (e >= NEDGES) return;
    int j = t & 31;
    int wide = flags[1];
    int s = ld_idx(ei, e, wide);
    int d = ld_idx(ei, NEDGES + e, wide);
    float w = dinv[s] * dinv[d];
    const float4 v = *reinterpret_cast<const float4*>(&tmp[(size_t)s * 128 + j * 4]);
    float* p = &agg[(size_t)d * 128 + j * 4];
    unsafeAtomicAdd(p + 0, v.x * w);
    unsafeAtomicAdd(p + 1, v.y * w);
    unsafeAtomicAdd(p + 2, v.z * w);
    unsafeAtomicAdd(p + 3, v.w * w);
}
__global__ void k_bias_relu(float* __restrict__ h, const void* __restrict__ b,
                            const int* __restrict__ flags) {
    int t = blockIdx.x * 256 + threadIdx.x;
    if (t >= NNODES * 32) return;
    int j = t & 31;
    float b0, b1, b2, b3;
    if (flags[0]) {
        const unsigned short* bb = (const unsigned short*)b;
        b0 = bfbits2f(bb[j * 4 + 0]); b1 = bfbits2f(bb[j * 4 + 1]);
        b2 = bfbits2f(bb[j * 4 + 2]); b3 = bfbits2f(bb[j * 4 + 3]);
    } else {
        const float* bb = (const float*)b;
        b0 = bb[j * 4 + 0]; b1 = bb[j * 4 + 1]; b2 = bb[j * 4 + 2]; b3 = bb[j * 4 + 3];
    }
    float4 v = *reinterpret_cast<float4*>(&h[(size_t)t * 4]);
    v.x = fmaxf(v.x + b0, 0.0f);
    v.y = fmaxf(v.y + b1, 0.0f);
    v.z = fmaxf(v.z + b2, 0.0f);
    v.w = fmaxf(v.w + b3, 0.0f);
    *reinterpret_cast<float4*>(&h[(size_t)t * 4]) = v;
}

// ---------------- pooling (bounds inlined via binary search) ----------------
// stage 1: 256 blocks = 4 segments x 64 graphs; bf16 h input; fp32 partials.
__global__ __launch_bounds__(256) void k_pool_part(const unsigned short* __restrict__ h16,
                                                   const int* __restrict__ batch,
                                                   const int* __restrict__ flags,
                                                   float* __restrict__ part) {
    __shared__ float sh[256 * 4];
    __shared__ int sbeg, send;
    int g = blockIdx.x >> 2, seg = blockIdx.x & 3;
    int t = threadIdx.x;
    int wide = flags[1];
    if (t == 0) sbeg = find_bound(batch, wide, g);
    if (t == 1) send = find_bound(batch, wide, g + 1);
    __syncthreads();
    int beg = sbeg, end = send;
    int c4 = t & 31, sub = t >> 5;
    const ushort4* __restrict__ base = (const ushort4*)h16;
    float ax = 0, ay = 0, az = 0, aw = 0;
    for (int r = beg + seg * 8 + sub; r < end; r += 32) {
        ushort4 u = base[(size_t)r * 32 + c4];
        ax += bfbits2f(u.x); ay += bfbits2f(u.y);
        az += bfbits2f(u.z); aw += bfbits2f(u.w);
    }
    sh[t * 4 + 0] = ax; sh[t * 4 + 1] = ay; sh[t * 4 + 2] = az; sh[t * 4 + 3] = aw;
    __syncthreads();
    if (t < 32) {
        float4 r = make_float4(0, 0, 0, 0);
#pragma unroll
        for (int s = 0; s < 8; ++s) {
            r.x += sh[(s * 32 + t) * 4 + 0];
            r.y += sh[(s * 32 + t) * 4 + 1];
            r.z += sh[(s * 32 + t) * 4 + 2];
            r.w += sh[(s * 32 + t) * 4 + 3];
        }
        *reinterpret_cast<float4*>(&part[((size_t)(g * 4 + seg)) * 128 + t * 4]) = r;
    }
}

__global__ void k_pool_final(const float* __restrict__ part, const int* __restrict__ batch,
                             const int* __restrict__ flags, void* __restrict__ out) {
    int i = blockIdx.x * 256 + threadIdx.x;
    if (i >= NGRAPH * 128) return;
    int g = i >> 7, col = i & 127;
    int wide = flags[1];
    float s = part[(g * 4 + 0) * 128 + col] + part[(g * 4 + 1) * 128 + col] +
              part[(g * 4 + 2) * 128 + col] + part[(g * 4 + 3) * 128 + col];
    float c = (float)(find_bound(batch, wide, g + 1) - find_bound(batch, wide, g));
    float r = s / fmaxf(c, 1.0f);
    if (flags[0]) ((__hip_bfloat16*)out)[i] = __float2bfloat16(r);
    else          ((float*)out)[i] = r;
}

// fallback pool (fp32 h)
__global__ __launch_bounds__(1024) void k_pool2(const float* __restrict__ h,
                                                const int* __restrict__ batch,
                                                const int* __restrict__ flags,
                                                void* __restrict__ out) {
    __shared__ float sh[1024];
    __shared__ int sbeg, send;
    int g = blockIdx.x;
    int t = threadIdx.x;
    int wide = flags[1];
    if (t == 0) sbeg = find_bound(batch, wide, g);
    if (t == 1) send = find_bound(batch, wide, g + 1);
    __syncthreads();
    int beg = sbeg, end = send;
    int col = t & 127, seg = t >> 7;
    float acc = 0.0f;
    for (int r = beg + seg; r < end; r += 8)
        acc += h[(size_t)r * 128 + col];
    sh[t] = acc;
    __syncthreads();
    if (t < 128) {
        float total = 0.0f;
#pragma unroll
        for (int i = 0; i < 8; ++i) total += sh[t + 128 * i];
        float c = (float)(end - beg);
        float r = total / fmaxf(c, 1.0f);
        if (flags[0]) ((__hip_bfloat16*)out)[g * 128 + t] = __float2bfloat16(r);
        else          ((float*)out)[g * 128 + t] = r;
    }
}

extern "C" void kernel_launch(void* const* d_in, const int* in_sizes, int n_in,
                              void* d_out, int out_size, void* d_ws, size_t ws_size,
                              hipStream_t stream) {
    const void* x  = d_in[0];
    const int* ei  = (const int*)d_in[1];
    const int* bat = (const int*)d_in[2];
    const void* W0 = d_in[3];
    const void* b0 = d_in[4];
    const void* W1 = d_in[5];
    const void* b1 = d_in[6];
    const void* W2 = d_in[7];
    const void* b2 = d_in[8];

    float* ws = (float*)d_ws;
    size_t off = 0;
    int*   flags  = (int*)ws;           off += 16;
    float* dinv   = ws + off;           off += 50176;   // fallback only
    float* hA     = ws + off;           off += (size_t)NNODES * 128;
    float* hB     = ws + off;           off += (size_t)NNODES * 128;
    int*   cnt    = (int*)(ws + off);   off += 50304;
    float* part   = ws + off;           off += NGRAPH * 4 * 128 + 64;
    const size_t needed = off * 4;
    unsigned short* hA16 = (unsigned short*)hA;
    unsigned short* hB16 = (unsigned short*)hB;
    unsigned short* ecol = (unsigned short*)(hA + (size_t)NNODES * 64);  // upper half of hA region

    const int bN  = (NNODES + 255) / 256;       // 196
    const int bE  = (NEDGES + 255) / 256;       // 3125
    const int bNF = (NNODES * 32) / 256;        // 6250
    const int bEF = (NEDGES * 32) / 256;        // 100000
    const int bA  = (NEDGES / 2 + 255) / 256;   // 1563 (append)
    const int bG  = (NNODES + 31) / 32;         // 1563 (vector gemm)
    const int bG2 = (NNODES + 63) / 64;         // 782  (mfma gemm / fused)
    dim3 blk(256);

    hipLaunchKernelGGL(k_detect, dim3(1), blk, 0, stream,
                       (const unsigned int*)x, (const unsigned int*)ei, flags);

    const bool use_csr = (ws_size >= needed);

    if (use_csr) {
        // bucket-CSR: zero counts -> single append pass
        hipLaunchKernelGGL(k_zero_int, dim3(bN), blk, 0, stream, cnt, 50176);
        hipLaunchKernelGGL(k_append, dim3(bA), blk, 0, stream, ei, flags, cnt, ecol);

        // layer 0 gemm: x @ W0, prescaled -> hA16
        hipLaunchKernelGGL(k_gemm_mfma, dim3(bG2), blk, 0, stream, x, W0, flags, 1, cnt, hA16, NNODES);
        // fused layers 1,2: gather(+bias+relu) into LDS -> gemm -> prescaled tmp
        hipLaunchKernelGGL(k_fused, dim3(bG2), blk, 0, stream, hA16, W1, flags, cnt, ecol, b0, hB16, NNODES);
        hipLaunchKernelGGL(k_fused, dim3(bG2), blk, 0, stream, hB16, W2, flags, cnt, ecol, b1, hA16, NNODES);
        // final gather -> h3 (bf16)
        hipLaunchKernelGGL(k_gather, dim3(bNF), blk, 0, stream, cnt, ecol, hA16, b2, flags, hB16);

        // pool: 2-stage reduce with inlined bounds
        hipLaunchKernelGGL(k_pool_part, dim3(NGRAPH * 4), blk, 0, stream, hB16, bat, flags, part);
        hipLaunchKernelGGL(k_pool_final, dim3(32), blk, 0, stream, part, bat, flags, d_out);
    } else {
        // fallback: round-3 proven atomic path (fp32 everywhere)
        hipLaunchKernelGGL(k_deg_init, dim3(bN), blk, 0, stream, dinv);
        hipLaunchKernelGGL(k_deg_edges, dim3(bE), blk, 0, stream, ei, flags, dinv);
        hipLaunchKernelGGL(k_rsqrt, dim3(bN), blk, 0, stream, dinv);

        hipLaunchKernelGGL(k_gemm, dim3(bG), blk, 0, stream, x, W0, flags, 1, hA, NNODES);
        hipLaunchKernelGGL(k_selfloop, dim3(bNF), blk, 0, stream, hA, dinv, hB);
        hipLaunchKernelGGL(k_scatter, dim3(bEF), blk, 0, stream, ei, flags, dinv, hA, hB);
        hipLaunchKernelGGL(k_bias_relu, dim3(bNF), blk, 0, stream, hB, b0, flags);

        hipLaunchKernelGGL(k_gemm, dim3(bG), blk, 0, stream, hB, W1, flags, 0, hA, NNODES);
        hipLaunchKernelGGL(k_selfloop, dim3(bNF), blk, 0, stream, hA, dinv, hB);
        hipLaunchKernelGGL(k_scatter, dim3(bEF), blk, 0, stream, ei, flags, dinv, hA, hB);
        hipLaunchKernelGGL(k_bias_relu, dim3(bNF), blk, 0, stream, hB, b1, flags);

        hipLaunchKernelGGL(k_gemm, dim3(bG), blk, 0, stream, hB, W2, flags, 0, hA, NNODES);
        hipLaunchKernelGGL(k_selfloop, dim3(bNF), blk, 0, stream, hA, dinv, hB);
        hipLaunchKernelGGL(k_scatter, dim3(bEF), blk, 0, stream, ei, flags, dinv, hA, hB);
        hipLaunchKernelGGL(k_bias_relu, dim3(bNF), blk, 0, stream, hB, b2, flags);

        hipLaunchKernelGGL(k_pool2, dim3(NGRAPH), dim3(1024), 0, stream, hB, bat, flags, d_out);
    }
}

// Round 12
// 342.517 us; speedup vs baseline: 1.1173x; 1.1173x over previous
//
#include <hip/hip_runtime.h>
#include <hip/hip_bf16.h>

#define NNODES 50000
#define NEDGES 800000
#define HIDDIM 128
#define NGRAPH 64
#define BUCKET 64  // fixed CSR bucket capacity (mean deg 16, P(deg>=64)~2e-18)

typedef __attribute__((ext_vector_type(8))) short short8;
typedef __attribute__((ext_vector_type(4))) float floatx4;

__device__ __forceinline__ float bfbits2f(unsigned short u) {
    return __uint_as_float(((unsigned int)u) << 16);
}
__device__ __forceinline__ unsigned short f2bfbits(float v) {
    __hip_bfloat16 h = __float2bfloat16(v);
    return __builtin_bit_cast(unsigned short, h);
}

// ---------------- runtime dtype detection (parallel) ----------------
// flags[0]=1: floats stored bf16; 0: fp32.  flags[1]=1: indices int64; 0: int32.
__global__ void k_detect(const unsigned int* __restrict__ xw,
                         const unsigned int* __restrict__ eiw,
                         int* __restrict__ flags) {
    __shared__ int sh_hit, sh_zero;
    int t = threadIdx.x;
    if (t == 0) { sh_hit = 0; sh_zero = 0; }
    __syncthreads();
    if (t < 128) {
        unsigned int w = xw[t * 97 + 5];
        int e = (int)((w >> 7) & 0xFF);
        if (e >= 110 && e <= 140) atomicAdd(&sh_hit, 1);
        if (eiw[1001 + 2 * t] == 0) atomicAdd(&sh_zero, 1);
    }
    __syncthreads();
    if (t == 0) {
        flags[0] = (sh_hit >= 64) ? 1 : 0;
        flags[1] = (sh_zero >= 120) ? 1 : 0;
    }
}

__device__ __forceinline__ int ld_idx(const int* __restrict__ p, int j, int wide) {
    return wide ? p[2 * j] : p[j];
}

__device__ __forceinline__ int find_bound(const int* __restrict__ batch, int wide, int g) {
    int lo = 0, hi = NNODES;
    while (lo < hi) {
        int mid = (lo + hi) >> 1;
        if (ld_idx(batch, mid, wide) < g) lo = mid + 1; else hi = mid;
    }
    return lo;
}

// ---------------- bucket-CSR build (single append pass, ushort entries) ------------
__global__ void k_zero_int(int* __restrict__ p, int n) {
    int i = blockIdx.x * 256 + threadIdx.x;
    if (i < n) p[i] = 0;
}

// 2 edges per thread; ushort ecol: a mean-16 bucket fits ONE 64B line -> L2-coalesced.
__global__ void k_append(const int* __restrict__ ei, const int* __restrict__ flags,
                         int* __restrict__ cnt, unsigned short* __restrict__ ecol) {
    int t = blockIdx.x * 256 + threadIdx.x;
    int e0 = t * 2;
    if (e0 >= NEDGES) return;
    int wide = flags[1];
    int s0, s1, d0, d1;
    if (wide) {
        int4 sv = ((const int4*)ei)[t];
        s0 = sv.x; s1 = sv.z;
        int4 dv = ((const int4*)(ei + 2 * NEDGES))[t];
        d0 = dv.x; d1 = dv.z;
    } else {
        int2 sv = ((const int2*)ei)[t];
        s0 = sv.x; s1 = sv.y;
        int2 dv = ((const int2*)(ei + NEDGES))[t];
        d0 = dv.x; d1 = dv.y;
    }
    int p0 = atomicAdd(&cnt[d0], 1);
    if (p0 < BUCKET) ecol[d0 * BUCKET + p0] = (unsigned short)s0;
    int p1 = atomicAdd(&cnt[d1], 1);
    if (p1 < BUCKET) ecol[d1 * BUCKET + p1] = (unsigned short)s1;
}

// ---------------- MFMA GEMM: out_bf16[M,128] = (A @ W) * rsqrt(cnt[m]+1)? ----------
// a_mode: 0=fp32 A, 1=A follows flags[0], 2=A is bf16 bits.  cntScale nullable.
// Layouts (m89/m120-verified): A m=lane&15,k=quad*8+j ; B k=quad*8+j,n=lane&15 ;
// D row=quad*4+i, col=lane&15.
__global__ __launch_bounds__(256) void k_gemm_mfma(const void* __restrict__ A,
                                                   const void* __restrict__ W,
                                                   const int* __restrict__ flags,
                                                   int a_mode,
                                                   const int* __restrict__ cntScale,
                                                   unsigned short* __restrict__ out,
                                                   int M) {
    __shared__ __align__(16) unsigned short Wl[16 * 128 * 8];   // 32 KB: [kb][n][j]
    __shared__ __align__(16) unsigned short Alds[64 * 17 * 8];  // 17 KB: [m][kb(+pad)][j]
    const int tid = threadIdx.x;
    const int F = flags[0];
    const int abf = (a_mode == 2) ? 1 : (a_mode == 1 ? F : 0);
    const int row0 = blockIdx.x * 64;

    if (F) {
        const ushort4* __restrict__ Wg = (const ushort4*)W;
#pragma unroll
        for (int it = 0; it < 16; ++it) {
            int idx = it * 256 + tid;
            int k = idx >> 5, n = (idx & 31) * 4;
            ushort4 wv = Wg[idx];
            unsigned short* dst = &Wl[(((k >> 3) * 128) + n) * 8 + (k & 7)];
            dst[0] = wv.x; dst[8] = wv.y; dst[16] = wv.z; dst[24] = wv.w;
        }
    } else {
        const float4* __restrict__ Wg = (const float4*)W;
#pragma unroll
        for (int it = 0; it < 16; ++it) {
            int idx = it * 256 + tid;
            int k = idx >> 5, n = (idx & 31) * 4;
            float4 wv = Wg[idx];
            unsigned short* dst = &Wl[(((k >> 3) * 128) + n) * 8 + (k & 7)];
            dst[0] = f2bfbits(wv.x); dst[8]  = f2bfbits(wv.y);
            dst[16] = f2bfbits(wv.z); dst[24] = f2bfbits(wv.w);
        }
    }
    if (abf) {
#pragma unroll
        for (int it = 0; it < 4; ++it) {
            int idx = it * 256 + tid;
            int m = idx >> 4, kb = idx & 15;
            int gr = row0 + m;
            uint4 v = make_uint4(0, 0, 0, 0);
            if (gr < M) v = ((const uint4*)A)[(size_t)gr * 16 + kb];
            *reinterpret_cast<uint4*>(&Alds[(m * 17 + kb) * 8]) = v;
        }
    } else {
#pragma unroll
        for (int it = 0; it < 8; ++it) {
            int idx = it * 256 + tid;
            int m = idx >> 5, k4 = idx & 31;
            int k = k4 * 4;
            int gr = row0 + m;
            float4 v = make_float4(0, 0, 0, 0);
            if (gr < M) v = ((const float4*)A)[(size_t)gr * 32 + k4];
            ushort4 u;
            u.x = f2bfbits(v.x); u.y = f2bfbits(v.y);
            u.z = f2bfbits(v.z); u.w = f2bfbits(v.w);
            *reinterpret_cast<ushort4*>(&Alds[(m * 17 + (k >> 3)) * 8 + (k & 7)]) = u;
        }
    }
    __syncthreads();

    const int lane = tid & 63;
    const int wave = tid >> 6;
    const int q = lane >> 4;
    const int c = lane & 15;
    const int mrow = wave * 16 + c;
    floatx4 acc[8] = {};
#pragma unroll
    for (int k0 = 0; k0 < 4; ++k0) {
        int kb = k0 * 4 + q;
        short8 afrag = *reinterpret_cast<const short8*>(&Alds[(mrow * 17 + kb) * 8]);
#pragma unroll
        for (int t = 0; t < 8; ++t) {
            short8 bfrag = *reinterpret_cast<const short8*>(&Wl[(kb * 128 + t * 16 + c) * 8]);
            acc[t] = __builtin_amdgcn_mfma_f32_16x16x32_bf16(afrag, bfrag, acc[t], 0, 0, 0);
        }
    }
#pragma unroll
    for (int i = 0; i < 4; ++i) {
        int gr = row0 + wave * 16 + q * 4 + i;
        if (gr < M) {
            float s = cntScale ? rsqrtf((float)cntScale[gr] + 1.0f) : 1.0f;
#pragma unroll
            for (int t = 0; t < 8; ++t) {
                out[(size_t)gr * 128 + t * 16 + c] = f2bfbits(acc[t][i] * s);
            }
        }
    }
}

// ---------------- gather (bf16 in/out): row-sum + rsqrt scale + bias + relu --------
// tmp16 rows pre-scaled by dinv[src]; fixed buckets ecol[n*64 + 0..cnt[n]) (ushort).
// Split from the GEMM on purpose: this kernel is latency-bound and needs the ~70%
// occupancy it gets at 16 VGPR / 0 LDS (round-11 fusion dropped it to 19% -> 2x slower).
__global__ __launch_bounds__(256) void k_gather(const int* __restrict__ cnt,
                                                const unsigned short* __restrict__ ecol,
                                                const unsigned short* __restrict__ tmp16,
                                                const void* __restrict__ bias,
                                                const int* __restrict__ flags,
                                                unsigned short* __restrict__ outh16) {
    int t = blockIdx.x * 256 + threadIdx.x;
    int n = t >> 5;
    if (n >= NNODES) return;
    int j = t & 31;
    int rawc = cnt[n];
    int deg = rawc > BUCKET ? BUCKET : rawc;
    const unsigned short* __restrict__ bk = &ecol[n * BUCKET];
    const ushort4* __restrict__ base = reinterpret_cast<const ushort4*>(tmp16);
    ushort4 u = base[(size_t)n * 32 + j];  // self-loop term (pre-scaled)
    float ax = bfbits2f(u.x), ay = bfbits2f(u.y), az = bfbits2f(u.z), aw = bfbits2f(u.w);
    int k = 0;
    for (; k + 3 < deg; k += 4) {
        ushort4 sv = *reinterpret_cast<const ushort4*>(&bk[k]);  // bucket 128B-aligned
        ushort4 u0 = base[(size_t)sv.x * 32 + j];
        ushort4 u1 = base[(size_t)sv.y * 32 + j];
        ushort4 u2 = base[(size_t)sv.z * 32 + j];
        ushort4 u3 = base[(size_t)sv.w * 32 + j];
        ax += (bfbits2f(u0.x) + bfbits2f(u1.x)) + (bfbits2f(u2.x) + bfbits2f(u3.x));
        ay += (bfbits2f(u0.y) + bfbits2f(u1.y)) + (bfbits2f(u2.y) + bfbits2f(u3.y));
        az += (bfbits2f(u0.z) + bfbits2f(u1.z)) + (bfbits2f(u2.z) + bfbits2f(u3.z));
        aw += (bfbits2f(u0.w) + bfbits2f(u1.w)) + (bfbits2f(u2.w) + bfbits2f(u3.w));
    }
    for (; k < deg; ++k) {
        ushort4 u0 = base[(size_t)bk[k] * 32 + j];
        ax += bfbits2f(u0.x); ay += bfbits2f(u0.y);
        az += bfbits2f(u0.z); aw += bfbits2f(u0.w);
    }
    float dn = rsqrtf((float)rawc + 1.0f);
    ax *= dn; ay *= dn; az *= dn; aw *= dn;
    float b0, b1, b2, b3;
    if (flags[0]) {
        const unsigned short* bb = (const unsigned short*)bias;
        b0 = bfbits2f(bb[j * 4 + 0]); b1 = bfbits2f(bb[j * 4 + 1]);
        b2 = bfbits2f(bb[j * 4 + 2]); b3 = bfbits2f(bb[j * 4 + 3]);
    } else {
        const float* bb = (const float*)bias;
        b0 = bb[j * 4 + 0]; b1 = bb[j * 4 + 1]; b2 = bb[j * 4 + 2]; b3 = bb[j * 4 + 3];
    }
    ushort4 o;
    o.x = f2bfbits(fmaxf(ax + b0, 0.0f));
    o.y = f2bfbits(fmaxf(ay + b1, 0.0f));
    o.z = f2bfbits(fmaxf(az + b2, 0.0f));
    o.w = f2bfbits(fmaxf(aw + b3, 0.0f));
    reinterpret_cast<ushort4*>(outh16)[(size_t)n * 32 + j] = o;
}

// ---------------- fallback (round-3 proven) atomic-scatter path ----------------
__global__ __launch_bounds__(256) void k_gemm(const void* __restrict__ A,
                                              const void* __restrict__ W,
                                              const int* __restrict__ flags,
                                              int a_uses_flag,
                                              float* __restrict__ out, int M) {
    __shared__ __align__(16) float Al[32 * 128];
    const int tid = threadIdx.x;
    const int F = flags[0];
    const int afmt = a_uses_flag ? F : 0;
    const int row0 = blockIdx.x * 32;
#pragma unroll
    for (int j = 0; j < 16; ++j) {
        int idx = j * 256 + tid;
        int r = idx >> 7, k = idx & 127;
        int gr = row0 + r;
        float v = 0.0f;
        if (gr < M) {
            size_t off = (size_t)gr * 128 + k;
            v = afmt ? bfbits2f(((const unsigned short*)A)[off])
                     : ((const float*)A)[off];
        }
        Al[idx] = v;
    }
    __syncthreads();
    const int tx = tid & 31, ty = tid >> 5;
    const int c0 = tx * 4;
    float acc[4][4] = {};
    if (F) {
        const ushort4* __restrict__ Wg = (const ushort4*)W;
#pragma unroll 4
        for (int k = 0; k < 128; ++k) {
            ushort4 wv = Wg[k * 32 + tx];
            float w0 = bfbits2f(wv.x), w1 = bfbits2f(wv.y);
            float w2 = bfbits2f(wv.z), w3 = bfbits2f(wv.w);
#pragma unroll
            for (int i = 0; i < 4; ++i) {
                float a = Al[(ty + i * 8) * 128 + k];
                acc[i][0] = fmaf(a, w0, acc[i][0]);
                acc[i][1] = fmaf(a, w1, acc[i][1]);
                acc[i][2] = fmaf(a, w2, acc[i][2]);
                acc[i][3] = fmaf(a, w3, acc[i][3]);
            }
        }
    } else {
        const float4* __restrict__ Wg = (const float4*)W;
#pragma unroll 4
        for (int k = 0; k < 128; ++k) {
            float4 wv = Wg[k * 32 + tx];
#pragma unroll
            for (int i = 0; i < 4; ++i) {
                float a = Al[(ty + i * 8) * 128 + k];
                acc[i][0] = fmaf(a, wv.x, acc[i][0]);
                acc[i][1] = fmaf(a, wv.y, acc[i][1]);
                acc[i][2] = fmaf(a, wv.z, acc[i][2]);
                acc[i][3] = fmaf(a, wv.w, acc[i][3]);
            }
        }
    }
#pragma unroll
    for (int i = 0; i < 4; ++i) {
        int gr = row0 + ty + i * 8;
        if (gr < M) {
            *reinterpret_cast<float4*>(&out[(size_t)gr * 128 + c0]) =
                make_float4(acc[i][0], acc[i][1], acc[i][2], acc[i][3]);
        }
    }
}
__global__ void k_deg_init(float* __restrict__ deg) {
    int i = blockIdx.x * 256 + threadIdx.x;
    if (i < NNODES) deg[i] = 1.0f;
}
__global__ void k_deg_edges(const int* __restrict__ ei, const int* __restrict__ flags,
                            float* __restrict__ deg) {
    int e = blockIdx.x * 256 + threadIdx.x;
    if (e < NEDGES) unsafeAtomicAdd(&deg[ld_idx(ei, NEDGES + e, flags[1])], 1.0f);
}
__global__ void k_rsqrt(float* __restrict__ deg) {
    int i = blockIdx.x * 256 + threadIdx.x;
    if (i < NNODES) deg[i] = 1.0f / sqrtf(deg[i]);
}
__global__ void k_selfloop(const float* __restrict__ tmp, const float* __restrict__ dinv,
                           float* __restrict__ agg) {
    int t = blockIdx.x * 256 + threadIdx.x;
    if (t >= NNODES * 32) return;
    int n = t >> 5, j = t & 31;
    float s = dinv[n]; s = s * s;
    float4 v = *reinterpret_cast<const float4*>(&tmp[(size_t)n * 128 + j * 4]);
    v.x *= s; v.y *= s; v.z *= s; v.w *= s;
    *reinterpret_cast<float4*>(&agg[(size_t)n * 128 + j * 4]) = v;
}
__global__ __launch_bounds__(256) void k_scatter(const int* __restrict__ ei,
                                                 const int* __restrict__ flags,
                                                 const float* __restrict__ dinv,
                                                 const float* __restrict__ tmp,
                                                 float* __restrict__ agg) {
    int t = blockIdx.x * 256 + threadIdx.x;
    int e = t >> 5;
    if (e >= NEDGES) return;
    int j = t & 31;
    int wide = flags[1];
    int s = ld_idx(ei, e, wide);
    int d = ld_idx(ei, NEDGES + e, wide);
    float w = dinv[s] * dinv[d];
    const float4 v = *reinterpret_cast<const float4*>(&tmp[(size_t)s * 128 + j * 4]);
    float* p = &agg[(size_t)d * 128 + j * 4];
    unsafeAtomicAdd(p + 0, v.x * w);
    unsafeAtomicAdd(p + 1, v.y * w);
    unsafeAtomicAdd(p + 2, v.z * w);
    unsafeAtomicAdd(p + 3, v.w * w);
}
__global__ void k_bias_relu(float* __restrict__ h, const void* __restrict__ b,
                            const int* __restrict__ flags) {
    int t = blockIdx.x * 256 + threadIdx.x;
    if (t >= NNODES * 32) return;
    int j = t & 31;
    float b0, b1, b2, b3;
    if (flags[0]) {
        const unsigned short* bb = (const unsigned short*)b;
        b0 = bfbits2f(bb[j * 4 + 0]); b1 = bfbits2f(bb[j * 4 + 1]);
        b2 = bfbits2f(bb[j * 4 + 2]); b3 = bfbits2f(bb[j * 4 + 3]);
    } else {
        const float* bb = (const float*)b;
        b0 = bb[j * 4 + 0]; b1 = bb[j * 4 + 1]; b2 = bb[j * 4 + 2]; b3 = bb[j * 4 + 3];
    }
    float4 v = *reinterpret_cast<float4*>(&h[(size_t)t * 4]);
    v.x = fmaxf(v.x + b0, 0.0f);
    v.y = fmaxf(v.y + b1, 0.0f);
    v.z = fmaxf(v.z + b2, 0.0f);
    v.w = fmaxf(v.w + b3, 0.0f);
    *reinterpret_cast<float4*>(&h[(size_t)t * 4]) = v;
}

// ---------------- pooling (bounds inlined via binary search) ----------------
// stage 1: 256 blocks = 4 segments x 64 graphs; bf16 h input; fp32 partials.
__global__ __launch_bounds__(256) void k_pool_part(const unsigned short* __restrict__ h16,
                                                   const int* __restrict__ batch,
                                                   const int* __restrict__ flags,
                                                   float* __restrict__ part) {
    __shared__ float sh[256 * 4];
    __shared__ int sbeg, send;
    int g = blockIdx.x >> 2, seg = blockIdx.x & 3;
    int t = threadIdx.x;
    int wide = flags[1];
    if (t == 0) sbeg = find_bound(batch, wide, g);
    if (t == 1) send = find_bound(batch, wide, g + 1);
    __syncthreads();
    int beg = sbeg, end = send;
    int c4 = t & 31, sub = t >> 5;
    const ushort4* __restrict__ base = (const ushort4*)h16;
    float ax = 0, ay = 0, az = 0, aw = 0;
    for (int r = beg + seg * 8 + sub; r < end; r += 32) {
        ushort4 u = base[(size_t)r * 32 + c4];
        ax += bfbits2f(u.x); ay += bfbits2f(u.y);
        az += bfbits2f(u.z); aw += bfbits2f(u.w);
    }
    sh[t * 4 + 0] = ax; sh[t * 4 + 1] = ay; sh[t * 4 + 2] = az; sh[t * 4 + 3] = aw;
    __syncthreads();
    if (t < 32) {
        float4 r = make_float4(0, 0, 0, 0);
#pragma unroll
        for (int s = 0; s < 8; ++s) {
            r.x += sh[(s * 32 + t) * 4 + 0];
            r.y += sh[(s * 32 + t) * 4 + 1];
            r.z += sh[(s * 32 + t) * 4 + 2];
            r.w += sh[(s * 32 + t) * 4 + 3];
        }
        *reinterpret_cast<float4*>(&part[((size_t)(g * 4 + seg)) * 128 + t * 4]) = r;
    }
}

__global__ void k_pool_final(const float* __restrict__ part, const int* __restrict__ batch,
                             const int* __restrict__ flags, void* __restrict__ out) {
    int i = blockIdx.x * 256 + threadIdx.x;
    if (i >= NGRAPH * 128) return;
    int g = i >> 7, col = i & 127;
    int wide = flags[1];
    float s = part[(g * 4 + 0) * 128 + col] + part[(g * 4 + 1) * 128 + col] +
              part[(g * 4 + 2) * 128 + col] + part[(g * 4 + 3) * 128 + col];
    float c = (float)(find_bound(batch, wide, g + 1) - find_bound(batch, wide, g));
    float r = s / fmaxf(c, 1.0f);
    if (flags[0]) ((__hip_bfloat16*)out)[i] = __float2bfloat16(r);
    else          ((float*)out)[i] = r;
}

// fallback pool (fp32 h)
__global__ __launch_bounds__(1024) void k_pool2(const float* __restrict__ h,
                                                const int* __restrict__ batch,
                                                const int* __restrict__ flags,
                                                void* __restrict__ out) {
    __shared__ float sh[1024];
    __shared__ int sbeg, send;
    int g = blockIdx.x;
    int t = threadIdx.x;
    int wide = flags[1];
    if (t == 0) sbeg = find_bound(batch, wide, g);
    if (t == 1) send = find_bound(batch, wide, g + 1);
    __syncthreads();
    int beg = sbeg, end = send;
    int col = t & 127, seg = t >> 7;
    float acc = 0.0f;
    for (int r = beg + seg; r < end; r += 8)
        acc += h[(size_t)r * 128 + col];
    sh[t] = acc;
    __syncthreads();
    if (t < 128) {
        float total = 0.0f;
#pragma unroll
        for (int i = 0; i < 8; ++i) total += sh[t + 128 * i];
        float c = (float)(end - beg);
        float r = total / fmaxf(c, 1.0f);
        if (flags[0]) ((__hip_bfloat16*)out)[g * 128 + t] = __float2bfloat16(r);
        else          ((float*)out)[g * 128 + t] = r;
    }
}

extern "C" void kernel_launch(void* const* d_in, const int* in_sizes, int n_in,
                              void* d_out, int out_size, void* d_ws, size_t ws_size,
                              hipStream_t stream) {
    const void* x  = d_in[0];
    const int* ei  = (const int*)d_in[1];
    const int* bat = (const int*)d_in[2];
    const void* W0 = d_in[3];
    const void* b0 = d_in[4];
    const void* W1 = d_in[5];
    const void* b1 = d_in[6];
    const void* W2 = d_in[7];
    const void* b2 = d_in[8];

    float* ws = (float*)d_ws;
    size_t off = 0;
    int*   flags  = (int*)ws;           off += 16;
    float* dinv   = ws + off;           off += 50176;   // fallback only
    float* hA     = ws + off;           off += (size_t)NNODES * 128;
    float* hB     = ws + off;           off += (size_t)NNODES * 128;
    int*   cnt    = (int*)(ws + off);   off += 50304;
    float* part   = ws + off;           off += NGRAPH * 4 * 128 + 64;
    const size_t needed = off * 4;
    unsigned short* hA16 = (unsigned short*)hA;
    unsigned short* hB16 = (unsigned short*)hB;
    unsigned short* ecol = (unsigned short*)(hA + (size_t)NNODES * 64);  // upper half of hA region

    const int bN  = (NNODES + 255) / 256;       // 196
    const int bE  = (NEDGES + 255) / 256;       // 3125
    const int bNF = (NNODES * 32) / 256;        // 6250
    const int bEF = (NEDGES * 32) / 256;        // 100000
    const int bA  = (NEDGES / 2 + 255) / 256;   // 1563 (append)
    const int bG  = (NNODES + 31) / 32;         // 1563 (vector gemm)
    const int bG2 = (NNODES + 63) / 64;         // 782  (mfma gemm)
    dim3 blk(256);

    hipLaunchKernelGGL(k_detect, dim3(1), blk, 0, stream,
                       (const unsigned int*)x, (const unsigned int*)ei, flags);

    const bool use_csr = (ws_size >= needed);

    if (use_csr) {
        // bucket-CSR: zero counts -> single append pass (dinv folded into epilogues)
        hipLaunchKernelGGL(k_zero_int, dim3(bN), blk, 0, stream, cnt, 50176);
        hipLaunchKernelGGL(k_append, dim3(bA), blk, 0, stream, ei, flags, cnt, ecol);

        // layers: MFMA gemm (bf16 out, rsqrt(cnt+1)-prescaled) + gather (bf16 in/out)
        hipLaunchKernelGGL(k_gemm_mfma, dim3(bG2), blk, 0, stream, x,    W0, flags, 1, cnt, hA16, NNODES);
        hipLaunchKernelGGL(k_gather,    dim3(bNF), blk, 0, stream, cnt, ecol, hA16, b0, flags, hB16);
        hipLaunchKernelGGL(k_gemm_mfma, dim3(bG2), blk, 0, stream, hB16, W1, flags, 2, cnt, hA16, NNODES);
        hipLaunchKernelGGL(k_gather,    dim3(bNF), blk, 0, stream, cnt, ecol, hA16, b1, flags, hB16);
        hipLaunchKernelGGL(k_gemm_mfma, dim3(bG2), blk, 0, stream, hB16, W2, flags, 2, cnt, hA16, NNODES);
        hipLaunchKernelGGL(k_gather,    dim3(bNF), blk, 0, stream, cnt, ecol, hA16, b2, flags, hB16);

        // pool: 2-stage reduce, bounds inlined
        hipLaunchKernelGGL(k_pool_part, dim3(NGRAPH * 4), blk, 0, stream, hB16, bat, flags, part);
        hipLaunchKernelGGL(k_pool_final, dim3(32), blk, 0, stream, part, bat, flags, d_out);
    } else {
        // fallback: round-3 proven atomic path (fp32 everywhere)
        hipLaunchKernelGGL(k_deg_init, dim3(bN), blk, 0, stream, dinv);
        hipLaunchKernelGGL(k_deg_edges, dim3(bE), blk, 0, stream, ei, flags, dinv);
        hipLaunchKernelGGL(k_rsqrt, dim3(bN), blk, 0, stream, dinv);

        hipLaunchKernelGGL(k_gemm, dim3(bG), blk, 0, stream, x, W0, flags, 1, hA, NNODES);
        hipLaunchKernelGGL(k_selfloop, dim3(bNF), blk, 0, stream, hA, dinv, hB);
        hipLaunchKernelGGL(k_scatter, dim3(bEF), blk, 0, stream, ei, flags, dinv, hA, hB);
        hipLaunchKernelGGL(k_bias_relu, dim3(bNF), blk, 0, stream, hB, b0, flags);

        hipLaunchKernelGGL(k_gemm, dim3(bG), blk, 0, stream, hB, W1, flags, 0, hA, NNODES);
        hipLaunchKernelGGL(k_selfloop, dim3(bNF), blk, 0, stream, hA, dinv, hB);
        hipLaunchKernelGGL(k_scatter, dim3(bEF), blk, 0, stream, ei, flags, dinv, hA, hB);
        hipLaunchKernelGGL(k_bias_relu, dim3(bNF), blk, 0, stream, hB, b1, flags);

        hipLaunchKernelGGL(k_gemm, dim3(bG), blk, 0, stream, hB, W2, flags, 0, hA, NNODES);
        hipLaunchKernelGGL(k_selfloop, dim3(bNF), blk, 0, stream, hA, dinv, hB);
        hipLaunchKernelGGL(k_scatter, dim3(bEF), blk, 0, stream, ei, flags, dinv, hA, hB);
        hipLaunchKernelGGL(k_bias_relu, dim3(bNF), blk, 0, stream, hB, b2, flags);

        hipLaunchKernelGGL(k_pool2, dim3(NGRAPH), dim3(1024), 0, stream, hB, bat, flags, d_out);
    }
}

// Round 13
// 338.642 us; speedup vs baseline: 1.1301x; 1.0114x over previous
//
#include <hip/hip_runtime.h>
#include <hip/hip_bf16.h>

#define NNODES 50000
#define NEDGES 800000
#define HIDDIM 128
#define NGRAPH 64
#define BUCKET 64   // fixed CSR bucket capacity (mean deg 16, P(deg>=64)~2e-18)
#define NB_CNT 196  // ceil(50000/256) blocks to zero cnt

typedef __attribute__((ext_vector_type(8))) short short8;
typedef __attribute__((ext_vector_type(4))) float floatx4;

__device__ __forceinline__ float bfbits2f(unsigned short u) {
    return __uint_as_float(((unsigned int)u) << 16);
}
__device__ __forceinline__ unsigned short f2bfbits(float v) {
    __hip_bfloat16 h = __float2bfloat16(v);
    return __builtin_bit_cast(unsigned short, h);
}

__device__ __forceinline__ void detect_body(const unsigned int* __restrict__ xw,
                                            const unsigned int* __restrict__ eiw,
                                            int* __restrict__ flags) {
    __shared__ int sh_hit, sh_zero;
    int t = threadIdx.x;
    if (t == 0) { sh_hit = 0; sh_zero = 0; }
    __syncthreads();
    if (t < 128) {
        unsigned int w = xw[t * 97 + 5];
        int e = (int)((w >> 7) & 0xFF);
        if (e >= 110 && e <= 140) atomicAdd(&sh_hit, 1);
        if (eiw[1001 + 2 * t] == 0) atomicAdd(&sh_zero, 1);
    }
    __syncthreads();
    if (t == 0) {
        flags[0] = (sh_hit >= 64) ? 1 : 0;
        flags[1] = (sh_zero >= 120) ? 1 : 0;
    }
}

// ---------------- fallback detect (no cnt zeroing; safe for small ws) -------------
__global__ void k_detect(const unsigned int* __restrict__ xw,
                         const unsigned int* __restrict__ eiw,
                         int* __restrict__ flags) {
    if (blockIdx.x == 0) detect_body(xw, eiw, flags);
}

// ---------------- CSR-path init: detect (block NB_CNT) + zero cnt (blocks 0..) ----
__global__ void k_init(const unsigned int* __restrict__ xw,
                       const unsigned int* __restrict__ eiw,
                       int* __restrict__ flags, int* __restrict__ cnt) {
    if (blockIdx.x == NB_CNT) { detect_body(xw, eiw, flags); return; }
    int i = blockIdx.x * 256 + threadIdx.x;
    if (i < 50176) cnt[i] = 0;
}

__device__ __forceinline__ int ld_idx(const int* __restrict__ p, int j, int wide) {
    return wide ? p[2 * j] : p[j];
}

__device__ __forceinline__ int find_bound(const int* __restrict__ batch, int wide, int g) {
    int lo = 0, hi = NNODES;
    while (lo < hi) {
        int mid = (lo + hi) >> 1;
        if (ld_idx(batch, mid, wide) < g) lo = mid + 1; else hi = mid;
    }
    return lo;
}

// ---------------- bucket-CSR append, dst-range partitioned ----------------
// Pass p handles dst in [lo,hi): per-pass bucket working set 3.2 MB < 4 MiB XCD-L2,
// so same-bucket ushort writes coalesce in L2 before writeback (round-12 showed the
// unpartitioned 6.4 MB region thrashes: WRITE_SIZE ~ one 64B line per edge).
__global__ void k_append_part(const int* __restrict__ ei, const int* __restrict__ flags,
                              int* __restrict__ cnt, unsigned short* __restrict__ ecol,
                              int lo, int hi) {
    int t = blockIdx.x * 256 + threadIdx.x;
    int e0 = t * 2;
    if (e0 >= NEDGES) return;
    int wide = flags[1];
    int s0, s1, d0, d1;
    if (wide) {
        int4 sv = ((const int4*)ei)[t];
        s0 = sv.x; s1 = sv.z;
        int4 dv = ((const int4*)(ei + 2 * NEDGES))[t];
        d0 = dv.x; d1 = dv.z;
    } else {
        int2 sv = ((const int2*)ei)[t];
        s0 = sv.x; s1 = sv.y;
        int2 dv = ((const int2*)(ei + NEDGES))[t];
        d0 = dv.x; d1 = dv.y;
    }
    if (d0 >= lo && d0 < hi) {
        int p0 = atomicAdd(&cnt[d0], 1);
        if (p0 < BUCKET) ecol[d0 * BUCKET + p0] = (unsigned short)s0;
    }
    if (d1 >= lo && d1 < hi) {
        int p1 = atomicAdd(&cnt[d1], 1);
        if (p1 < BUCKET) ecol[d1 * BUCKET + p1] = (unsigned short)s1;
    }
}

// ---------------- MFMA GEMM: out_bf16[M,128] = (A @ W) * rsqrt(cnt[m]+1)? ----------
// a_mode: 0=fp32 A, 1=A follows flags[0], 2=A is bf16 bits.  cntScale nullable.
__global__ __launch_bounds__(256) void k_gemm_mfma(const void* __restrict__ A,
                                                   const void* __restrict__ W,
                                                   const int* __restrict__ flags,
                                                   int a_mode,
                                                   const int* __restrict__ cntScale,
                                                   unsigned short* __restrict__ out,
                                                   int M) {
    __shared__ __align__(16) unsigned short Wl[16 * 128 * 8];   // 32 KB: [kb][n][j]
    __shared__ __align__(16) unsigned short Alds[64 * 17 * 8];  // 17 KB: [m][kb(+pad)][j]
    const int tid = threadIdx.x;
    const int F = flags[0];
    const int abf = (a_mode == 2) ? 1 : (a_mode == 1 ? F : 0);
    const int row0 = blockIdx.x * 64;

    if (F) {
        const ushort4* __restrict__ Wg = (const ushort4*)W;
#pragma unroll
        for (int it = 0; it < 16; ++it) {
            int idx = it * 256 + tid;
            int k = idx >> 5, n = (idx & 31) * 4;
            ushort4 wv = Wg[idx];
            unsigned short* dst = &Wl[(((k >> 3) * 128) + n) * 8 + (k & 7)];
            dst[0] = wv.x; dst[8] = wv.y; dst[16] = wv.z; dst[24] = wv.w;
        }
    } else {
        const float4* __restrict__ Wg = (const float4*)W;
#pragma unroll
        for (int it = 0; it < 16; ++it) {
            int idx = it * 256 + tid;
            int k = idx >> 5, n = (idx & 31) * 4;
            float4 wv = Wg[idx];
            unsigned short* dst = &Wl[(((k >> 3) * 128) + n) * 8 + (k & 7)];
            dst[0] = f2bfbits(wv.x); dst[8]  = f2bfbits(wv.y);
            dst[16] = f2bfbits(wv.z); dst[24] = f2bfbits(wv.w);
        }
    }
    if (abf) {
#pragma unroll
        for (int it = 0; it < 4; ++it) {
            int idx = it * 256 + tid;
            int m = idx >> 4, kb = idx & 15;
            int gr = row0 + m;
            uint4 v = make_uint4(0, 0, 0, 0);
            if (gr < M) v = ((const uint4*)A)[(size_t)gr * 16 + kb];
            *reinterpret_cast<uint4*>(&Alds[(m * 17 + kb) * 8]) = v;
        }
    } else {
#pragma unroll
        for (int it = 0; it < 8; ++it) {
            int idx = it * 256 + tid;
            int m = idx >> 5, k4 = idx & 31;
            int k = k4 * 4;
            int gr = row0 + m;
            float4 v = make_float4(0, 0, 0, 0);
            if (gr < M) v = ((const float4*)A)[(size_t)gr * 32 + k4];
            ushort4 u;
            u.x = f2bfbits(v.x); u.y = f2bfbits(v.y);
            u.z = f2bfbits(v.z); u.w = f2bfbits(v.w);
            *reinterpret_cast<ushort4*>(&Alds[(m * 17 + (k >> 3)) * 8 + (k & 7)]) = u;
        }
    }
    __syncthreads();

    const int lane = tid & 63;
    const int wave = tid >> 6;
    const int q = lane >> 4;
    const int c = lane & 15;
    const int mrow = wave * 16 + c;
    floatx4 acc[8] = {};
#pragma unroll
    for (int k0 = 0; k0 < 4; ++k0) {
        int kb = k0 * 4 + q;
        short8 afrag = *reinterpret_cast<const short8*>(&Alds[(mrow * 17 + kb) * 8]);
#pragma unroll
        for (int t = 0; t < 8; ++t) {
            short8 bfrag = *reinterpret_cast<const short8*>(&Wl[(kb * 128 + t * 16 + c) * 8]);
            acc[t] = __builtin_amdgcn_mfma_f32_16x16x32_bf16(afrag, bfrag, acc[t], 0, 0, 0);
        }
    }
#pragma unroll
    for (int i = 0; i < 4; ++i) {
        int gr = row0 + wave * 16 + q * 4 + i;
        if (gr < M) {
            float s = cntScale ? rsqrtf((float)cntScale[gr] + 1.0f) : 1.0f;
#pragma unroll
            for (int t = 0; t < 8; ++t) {
                out[(size_t)gr * 128 + t * 16 + c] = f2bfbits(acc[t][i] * s);
            }
        }
    }
}

// ---------------- gather (bf16 in/out): row-sum + rsqrt scale + bias + relu --------
// Kept split from GEMM: latency-bound, needs ~70% occupancy (fusion -> 19%, 2x slower).
__global__ __launch_bounds__(256) void k_gather(const int* __restrict__ cnt,
                                                const unsigned short* __restrict__ ecol,
                                                const unsigned short* __restrict__ tmp16,
                                                const void* __restrict__ bias,
                                                const int* __restrict__ flags,
                                                unsigned short* __restrict__ outh16) {
    int t = blockIdx.x * 256 + threadIdx.x;
    int n = t >> 5;
    if (n >= NNODES) return;
    int j = t & 31;
    int rawc = cnt[n];
    int deg = rawc > BUCKET ? BUCKET : rawc;
    const unsigned short* __restrict__ bk = &ecol[n * BUCKET];
    const ushort4* __restrict__ base = reinterpret_cast<const ushort4*>(tmp16);
    ushort4 u = base[(size_t)n * 32 + j];  // self-loop term (pre-scaled)
    float ax = bfbits2f(u.x), ay = bfbits2f(u.y), az = bfbits2f(u.z), aw = bfbits2f(u.w);
    int k = 0;
    for (; k + 3 < deg; k += 4) {
        ushort4 sv = *reinterpret_cast<const ushort4*>(&bk[k]);
        ushort4 u0 = base[(size_t)sv.x * 32 + j];
        ushort4 u1 = base[(size_t)sv.y * 32 + j];
        ushort4 u2 = base[(size_t)sv.z * 32 + j];
        ushort4 u3 = base[(size_t)sv.w * 32 + j];
        ax += (bfbits2f(u0.x) + bfbits2f(u1.x)) + (bfbits2f(u2.x) + bfbits2f(u3.x));
        ay += (bfbits2f(u0.y) + bfbits2f(u1.y)) + (bfbits2f(u2.y) + bfbits2f(u3.y));
        az += (bfbits2f(u0.z) + bfbits2f(u1.z)) + (bfbits2f(u2.z) + bfbits2f(u3.z));
        aw += (bfbits2f(u0.w) + bfbits2f(u1.w)) + (bfbits2f(u2.w) + bfbits2f(u3.w));
    }
    for (; k < deg; ++k) {
        ushort4 u0 = base[(size_t)bk[k] * 32 + j];
        ax += bfbits2f(u0.x); ay += bfbits2f(u0.y);
        az += bfbits2f(u0.z); aw += bfbits2f(u0.w);
    }
    float dn = rsqrtf((float)rawc + 1.0f);
    ax *= dn; ay *= dn; az *= dn; aw *= dn;
    float b0, b1, b2, b3;
    if (flags[0]) {
        const unsigned short* bb = (const unsigned short*)bias;
        b0 = bfbits2f(bb[j * 4 + 0]); b1 = bfbits2f(bb[j * 4 + 1]);
        b2 = bfbits2f(bb[j * 4 + 2]); b3 = bfbits2f(bb[j * 4 + 3]);
    } else {
        const float* bb = (const float*)bias;
        b0 = bb[j * 4 + 0]; b1 = bb[j * 4 + 1]; b2 = bb[j * 4 + 2]; b3 = bb[j * 4 + 3];
    }
    ushort4 o;
    o.x = f2bfbits(fmaxf(ax + b0, 0.0f));
    o.y = f2bfbits(fmaxf(ay + b1, 0.0f));
    o.z = f2bfbits(fmaxf(az + b2, 0.0f));
    o.w = f2bfbits(fmaxf(aw + b3, 0.0f));
    reinterpret_cast<ushort4*>(outh16)[(size_t)n * 32 + j] = o;
}

// ---------------- fallback (round-3 proven) atomic-scatter path ----------------
__global__ __launch_bounds__(256) void k_gemm(const void* __restrict__ A,
                                              const void* __restrict__ W,
                                              const int* __restrict__ flags,
                                              int a_uses_flag,
                                              float* __restrict__ out, int M) {
    __shared__ __align__(16) float Al[32 * 128];
    const int tid = threadIdx.x;
    const int F = flags[0];
    const int afmt = a_uses_flag ? F : 0;
    const int row0 = blockIdx.x * 32;
#pragma unroll
    for (int j = 0; j < 16; ++j) {
        int idx = j * 256 + tid;
        int r = idx >> 7, k = idx & 127;
        int gr = row0 + r;
        float v = 0.0f;
        if (gr < M) {
            size_t off = (size_t)gr * 128 + k;
            v = afmt ? bfbits2f(((const unsigned short*)A)[off])
                     : ((const float*)A)[off];
        }
        Al[idx] = v;
    }
    __syncthreads();
    const int tx = tid & 31, ty = tid >> 5;
    const int c0 = tx * 4;
    float acc[4][4] = {};
    if (F) {
        const ushort4* __restrict__ Wg = (const ushort4*)W;
#pragma unroll 4
        for (int k = 0; k < 128; ++k) {
            ushort4 wv = Wg[k * 32 + tx];
            float w0 = bfbits2f(wv.x), w1 = bfbits2f(wv.y);
            float w2 = bfbits2f(wv.z), w3 = bfbits2f(wv.w);
#pragma unroll
            for (int i = 0; i < 4; ++i) {
                float a = Al[(ty + i * 8) * 128 + k];
                acc[i][0] = fmaf(a, w0, acc[i][0]);
                acc[i][1] = fmaf(a, w1, acc[i][1]);
                acc[i][2] = fmaf(a, w2, acc[i][2]);
                acc[i][3] = fmaf(a, w3, acc[i][3]);
            }
        }
    } else {
        const float4* __restrict__ Wg = (const float4*)W;
#pragma unroll 4
        for (int k = 0; k < 128; ++k) {
            float4 wv = Wg[k * 32 + tx];
#pragma unroll
            for (int i = 0; i < 4; ++i) {
                float a = Al[(ty + i * 8) * 128 + k];
                acc[i][0] = fmaf(a, wv.x, acc[i][0]);
                acc[i][1] = fmaf(a, wv.y, acc[i][1]);
                acc[i][2] = fmaf(a, wv.z, acc[i][2]);
                acc[i][3] = fmaf(a, wv.w, acc[i][3]);
            }
        }
    }
#pragma unroll
    for (int i = 0; i < 4; ++i) {
        int gr = row0 + ty + i * 8;
        if (gr < M) {
            *reinterpret_cast<float4*>(&out[(size_t)gr * 128 + c0]) =
                make_float4(acc[i][0], acc[i][1], acc[i][2], acc[i][3]);
        }
    }
}
__global__ void k_deg_init(float* __restrict__ deg) {
    int i = blockIdx.x * 256 + threadIdx.x;
    if (i < NNODES) deg[i] = 1.0f;
}
__global__ void k_deg_edges(const int* __restrict__ ei, const int* __restrict__ flags,
                            float* __restrict__ deg) {
    int e = blockIdx.x * 256 + threadIdx.x;
    if (e < NEDGES) unsafeAtomicAdd(&deg[ld_idx(ei, NEDGES + e, flags[1])], 1.0f);
}
__global__ void k_rsqrt(float* __restrict__ deg) {
    int i = blockIdx.x * 256 + threadIdx.x;
    if (i < NNODES) deg[i] = 1.0f / sqrtf(deg[i]);
}
__global__ void k_selfloop(const float* __restrict__ tmp, const float* __restrict__ dinv,
                           float* __restrict__ agg) {
    int t = blockIdx.x * 256 + threadIdx.x;
    if (t >= NNODES * 32) return;
    int n = t >> 5, j = t & 31;
    float s = dinv[n]; s = s * s;
    float4 v = *reinterpret_cast<const float4*>(&tmp[(size_t)n * 128 + j * 4]);
    v.x *= s; v.y *= s; v.z *= s; v.w *= s;
    *reinterpret_cast<float4*>(&agg[(size_t)n * 128 + j * 4]) = v;
}
__global__ __launch_bounds__(256) void k_scatter(const int* __restrict__ ei,
                                                 const int* __restrict__ flags,
                                                 const float* __restrict__ dinv,
                                                 const float* __restrict__ tmp,
                                                 float* __restrict__ agg) {
    int t = blockIdx.x * 256 + threadIdx.x;
    int e = t >> 5;
    if (e >= NEDGES) return;
    int j = t & 31;
    int wide = flags[1];
    int s = ld_idx(ei, e, wide);
    int d = ld_idx(ei, NEDGES + e, wide);
    float w = dinv[s] * dinv[d];
    const float4 v = *reinterpret_cast<const float4*>(&tmp[(size_t)s * 128 + j * 4]);
    float* p = &agg[(size_t)d * 128 + j * 4];
    unsafeAtomicAdd(p + 0, v.x * w);
    unsafeAtomicAdd(p + 1, v.y * w);
    unsafeAtomicAdd(p + 2, v.z * w);
    unsafeAtomicAdd(p + 3, v.w * w);
}
__global__ void k_bias_relu(float* __restrict__ h, const void* __restrict__ b,
                            const int* __restrict__ flags) {
    int t = blockIdx.x * 256 + threadIdx.x;
    if (t >= NNODES * 32) return;
    int j = t & 31;
    float b0, b1, b2, b3;
    if (flags[0]) {
        const unsigned short* bb = (const unsigned short*)b;
        b0 = bfbits2f(bb[j * 4 + 0]); b1 = bfbits2f(bb[j * 4 + 1]);
        b2 = bfbits2f(bb[j * 4 + 2]); b3 = bfbits2f(bb[j * 4 + 3]);
    } else {
        const float* bb = (const float*)b;
        b0 = bb[j * 4 + 0]; b1 = bb[j * 4 + 1]; b2 = bb[j * 4 + 2]; b3 = bb[j * 4 + 3];
    }
    float4 v = *reinterpret_cast<float4*>(&h[(size_t)t * 4]);
    v.x = fmaxf(v.x + b0, 0.0f);
    v.y = fmaxf(v.y + b1, 0.0f);
    v.z = fmaxf(v.z + b2, 0.0f);
    v.w = fmaxf(v.w + b3, 0.0f);
    *reinterpret_cast<float4*>(&h[(size_t)t * 4]) = v;
}

// ---------------- pooling (bounds inlined via binary search) ----------------
__global__ __launch_bounds__(256) void k_pool_part(const unsigned short* __restrict__ h16,
                                                   const int* __restrict__ batch,
                                                   const int* __restrict__ flags,
                                                   float* __restrict__ part) {
    __shared__ float sh[256 * 4];
    __shared__ int sbeg, send;
    int g = blockIdx.x >> 2, seg = blockIdx.x & 3;
    int t = threadIdx.x;
    int wide = flags[1];
    if (t == 0) sbeg = find_bound(batch, wide, g);
    if (t == 1) send = find_bound(batch, wide, g + 1);
    __syncthreads();
    int beg = sbeg, end = send;
    int c4 = t & 31, sub = t >> 5;
    const ushort4* __restrict__ base = (const ushort4*)h16;
    float ax = 0, ay = 0, az = 0, aw = 0;
    for (int r = beg + seg * 8 + sub; r < end; r += 32) {
        ushort4 u = base[(size_t)r * 32 + c4];
        ax += bfbits2f(u.x); ay += bfbits2f(u.y);
        az += bfbits2f(u.z); aw += bfbits2f(u.w);
    }
    sh[t * 4 + 0] = ax; sh[t * 4 + 1] = ay; sh[t * 4 + 2] = az; sh[t * 4 + 3] = aw;
    __syncthreads();
    if (t < 32) {
        float4 r = make_float4(0, 0, 0, 0);
#pragma unroll
        for (int s = 0; s < 8; ++s) {
            r.x += sh[(s * 32 + t) * 4 + 0];
            r.y += sh[(s * 32 + t) * 4 + 1];
            r.z += sh[(s * 32 + t) * 4 + 2];
            r.w += sh[(s * 32 + t) * 4 + 3];
        }
        *reinterpret_cast<float4*>(&part[((size_t)(g * 4 + seg)) * 128 + t * 4]) = r;
    }
}

__global__ void k_pool_final(const float* __restrict__ part, const int* __restrict__ batch,
                             const int* __restrict__ flags, void* __restrict__ out) {
    int i = blockIdx.x * 256 + threadIdx.x;
    if (i >= NGRAPH * 128) return;
    int g = i >> 7, col = i & 127;
    int wide = flags[1];
    float s = part[(g * 4 + 0) * 128 + col] + part[(g * 4 + 1) * 128 + col] +
              part[(g * 4 + 2) * 128 + col] + part[(g * 4 + 3) * 128 + col];
    float c = (float)(find_bound(batch, wide, g + 1) - find_bound(batch, wide, g));
    float r = s / fmaxf(c, 1.0f);
    if (flags[0]) ((__hip_bfloat16*)out)[i] = __float2bfloat16(r);
    else          ((float*)out)[i] = r;
}

// fallback pool (fp32 h)
__global__ __launch_bounds__(1024) void k_pool2(const float* __restrict__ h,
                                                const int* __restrict__ batch,
                                                const int* __restrict__ flags,
                                                void* __restrict__ out) {
    __shared__ float sh[1024];
    __shared__ int sbeg, send;
    int g = blockIdx.x;
    int t = threadIdx.x;
    int wide = flags[1];
    if (t == 0) sbeg = find_bound(batch, wide, g);
    if (t == 1) send = find_bound(batch, wide, g + 1);
    __syncthreads();
    int beg = sbeg, end = send;
    int col = t & 127, seg = t >> 7;
    float acc = 0.0f;
    for (int r = beg + seg; r < end; r += 8)
        acc += h[(size_t)r * 128 + col];
    sh[t] = acc;
    __syncthreads();
    if (t < 128) {
        float total = 0.0f;
#pragma unroll
        for (int i = 0; i < 8; ++i) total += sh[t + 128 * i];
        float c = (float)(end - beg);
        float r = total / fmaxf(c, 1.0f);
        if (flags[0]) ((__hip_bfloat16*)out)[g * 128 + t] = __float2bfloat16(r);
        else          ((float*)out)[g * 128 + t] = r;
    }
}

extern "C" void kernel_launch(void* const* d_in, const int* in_sizes, int n_in,
                              void* d_out, int out_size, void* d_ws, size_t ws_size,
                              hipStream_t stream) {
    const void* x  = d_in[0];
    const int* ei  = (const int*)d_in[1];
    const int* bat = (const int*)d_in[2];
    const void* W0 = d_in[3];
    const void* b0 = d_in[4];
    const void* W1 = d_in[5];
    const void* b1 = d_in[6];
    const void* W2 = d_in[7];
    const void* b2 = d_in[8];

    float* ws = (float*)d_ws;
    size_t off = 0;
    int*   flags  = (int*)ws;           off += 16;
    float* dinv   = ws + off;           off += 50176;   // fallback only
    float* hA     = ws + off;           off += (size_t)NNODES * 128;
    float* hB     = ws + off;           off += (size_t)NNODES * 128;
    int*   cnt    = (int*)(ws + off);   off += 50304;
    float* part   = ws + off;           off += NGRAPH * 4 * 128 + 64;
    const size_t needed = off * 4;
    unsigned short* hA16 = (unsigned short*)hA;
    unsigned short* hB16 = (unsigned short*)hB;
    unsigned short* ecol = (unsigned short*)(hA + (size_t)NNODES * 64);  // upper half of hA region

    const int bN  = (NNODES + 255) / 256;       // 196
    const int bE  = (NEDGES + 255) / 256;       // 3125
    const int bNF = (NNODES * 32) / 256;        // 6250
    const int bEF = (NEDGES * 32) / 256;        // 100000
    const int bA  = (NEDGES / 2 + 255) / 256;   // 1563 (append)
    const int bG  = (NNODES + 31) / 32;         // 1563 (vector gemm)
    const int bG2 = (NNODES + 63) / 64;         // 782  (mfma gemm)
    dim3 blk(256);

    const bool use_csr = (ws_size >= needed);

    if (use_csr) {
        // init: detect dtypes + zero cnt in one launch
        hipLaunchKernelGGL(k_init, dim3(NB_CNT + 1), blk, 0, stream,
                           (const unsigned int*)x, (const unsigned int*)ei, flags, cnt);
        // bucket-CSR append, dst-partitioned so each pass's buckets fit XCD L2
        hipLaunchKernelGGL(k_append_part, dim3(bA), blk, 0, stream, ei, flags, cnt, ecol,
                           0, NNODES / 2);
        hipLaunchKernelGGL(k_append_part, dim3(bA), blk, 0, stream, ei, flags, cnt, ecol,
                           NNODES / 2, NNODES);

        // layers: MFMA gemm (bf16 out, rsqrt(cnt+1)-prescaled) + gather (bf16 in/out)
        hipLaunchKernelGGL(k_gemm_mfma, dim3(bG2), blk, 0, stream, x,    W0, flags, 1, cnt, hA16, NNODES);
        hipLaunchKernelGGL(k_gather,    dim3(bNF), blk, 0, stream, cnt, ecol, hA16, b0, flags, hB16);
        hipLaunchKernelGGL(k_gemm_mfma, dim3(bG2), blk, 0, stream, hB16, W1, flags, 2, cnt, hA16, NNODES);
        hipLaunchKernelGGL(k_gather,    dim3(bNF), blk, 0, stream, cnt, ecol, hA16, b1, flags, hB16);
        hipLaunchKernelGGL(k_gemm_mfma, dim3(bG2), blk, 0, stream, hB16, W2, flags, 2, cnt, hA16, NNODES);
        hipLaunchKernelGGL(k_gather,    dim3(bNF), blk, 0, stream, cnt, ecol, hA16, b2, flags, hB16);

        // pool: 2-stage reduce, bounds inlined
        hipLaunchKernelGGL(k_pool_part, dim3(NGRAPH * 4), blk, 0, stream, hB16, bat, flags, part);
        hipLaunchKernelGGL(k_pool_final, dim3(32), blk, 0, stream, part, bat, flags, d_out);
    } else {
        // fallback: round-3 proven atomic path (fp32 everywhere)
        hipLaunchKernelGGL(k_detect, dim3(1), blk, 0, stream,
                           (const unsigned int*)x, (const unsigned int*)ei, flags);
        hipLaunchKernelGGL(k_deg_init, dim3(bN), blk, 0, stream, dinv);
        hipLaunchKernelGGL(k_deg_edges, dim3(bE), blk, 0, stream, ei, flags, dinv);
        hipLaunchKernelGGL(k_rsqrt, dim3(bN), blk, 0, stream, dinv);

        hipLaunchKernelGGL(k_gemm, dim3(bG), blk, 0, stream, x, W0, flags, 1, hA, NNODES);
        hipLaunchKernelGGL(k_selfloop, dim3(bNF), blk, 0, stream, hA, dinv, hB);
        hipLaunchKernelGGL(k_scatter, dim3(bEF), blk, 0, stream, ei, flags, dinv, hA, hB);
        hipLaunchKernelGGL(k_bias_relu, dim3(bNF), blk, 0, stream, hB, b0, flags);

        hipLaunchKernelGGL(k_gemm, dim3(bG), blk, 0, stream, hB, W1, flags, 0, hA, NNODES);
        hipLaunchKernelGGL(k_selfloop, dim3(bNF), blk, 0, stream, hA, dinv, hB);
        hipLaunchKernelGGL(k_scatter, dim3(bEF), blk, 0, stream, ei, flags, dinv, hA, hB);
        hipLaunchKernelGGL(k_bias_relu, dim3(bNF), blk, 0, stream, hB, b1, flags);

        hipLaunchKernelGGL(k_gemm, dim3(bG), blk, 0, stream, hB, W2, flags, 0, hA, NNODES);
        hipLaunchKernelGGL(k_selfloop, dim3(bNF), blk, 0, stream, hA, dinv, hB);
        hipLaunchKernelGGL(k_scatter, dim3(bEF), blk, 0, stream, ei, flags, dinv, hA, hB);
        hipLaunchKernelGGL(k_bias_relu, dim3(bNF), blk, 0, stream, hB, b2, flags);

        hipLaunchKernelGGL(k_pool2, dim3(NGRAPH), dim3(1024), 0, stream, hB, bat, flags, d_out);
    }
}